// Round 10
// baseline (575.868 us; speedup 1.0000x reference)
//
#include <hip/hip_runtime.h>

#define NN 30000
#define NE 480000
#define NG 512
#define MAXD 48
#define BATCH 16
#define NB 1875   // ceil(30000/16)
#define WPAD 132  // W_hh LDS row stride (shorts): 66 words -> bank 2*lc, conflict-free
#define HPAD2 132 // h_s row stride (shorts)
#define PROW 520  // pbuf row stride (shorts): 1040B -> lq groups 2-way max
#define HPAD 144  // k_proj x-stage row stride
#define NGB 469   // ceil(30000/64) for the 64-row GEMM kernels

typedef __attribute__((ext_vector_type(8))) short short8;
typedef __attribute__((ext_vector_type(4))) short s16x4;
typedef __attribute__((ext_vector_type(4))) float f32x4;

static __device__ __forceinline__ short f2bs(float f) {
  unsigned u = __builtin_bit_cast(unsigned, f);
  u = (u + 0x7fffu + ((u >> 16) & 1u)) >> 16;
  return (short)u;
}
static __device__ __forceinline__ float bs2f(short s) {
  unsigned u = ((unsigned)(unsigned short)s) << 16;
  return __builtin_bit_cast(float, u);
}
static __device__ __forceinline__ float sigf(float x) {
  return __builtin_amdgcn_rcpf(1.0f + __expf(-x));
}
static __device__ __forceinline__ float tanh_(float x) {
  return 1.0f - 2.0f * __builtin_amdgcn_rcpf(1.0f + __expf(2.0f * x));
}
// r9-passing hazard-safe AGPR-B MFMA block (kept for k_proj only)
static __device__ __forceinline__ void mfma_dual4(
    short8 a0, short8 a1, short8 a2, short8 a3,
    short8 b00, short8 b01, short8 b02, short8 b03,
    short8 b10, short8 b11, short8 b12, short8 b13,
    f32x4& c0, f32x4& c1) {
  asm("s_nop 1\n\t"
      "v_mfma_f32_16x16x32_bf16 %0, %2, %6, %0\n\t"
      "v_mfma_f32_16x16x32_bf16 %1, %2, %10, %1\n\t"
      "v_mfma_f32_16x16x32_bf16 %0, %3, %7, %0\n\t"
      "v_mfma_f32_16x16x32_bf16 %1, %3, %11, %1\n\t"
      "v_mfma_f32_16x16x32_bf16 %0, %4, %8, %0\n\t"
      "v_mfma_f32_16x16x32_bf16 %1, %4, %12, %1\n\t"
      "v_mfma_f32_16x16x32_bf16 %0, %5, %9, %0\n\t"
      "v_mfma_f32_16x16x32_bf16 %1, %5, %13, %1\n\t"
      "s_nop 7"
      : "+v"(c0), "+v"(c1)
      : "v"(a0), "v"(a1), "v"(a2), "v"(a3),
        "a"(b00), "a"(b01), "a"(b02), "a"(b03),
        "a"(b10), "a"(b11), "a"(b12), "a"(b13));
}
// async 16B-per-lane into LDS: dest = ldsbase + lane*16
static __device__ __forceinline__ void gl_lds16(const short* g, short* l) {
  __builtin_amdgcn_global_load_lds(
      (const __attribute__((address_space(1))) void*)g,
      (__attribute__((address_space(3))) void*)l, 16, 0, 0);
}

// ---- prep: segment starts/ends via boundary detection (src sorted) ----
__global__ void k_edges(const int* __restrict__ src, int* __restrict__ starts,
                        int* __restrict__ ends) {
  int e = blockIdx.x * 256 + threadIdx.x;
  if (e >= NE) return;
  int s = src[e];
  if (e == 0 || src[e - 1] != s) starts[s] = e;
  if (e == NE - 1 || src[e + 1] != s) ends[s] = e + 1;
}

__global__ void k_hs(const int* __restrict__ starts, const int* __restrict__ ends,
                     int* __restrict__ offs) {
  __shared__ int hist[MAXD + 1];
  int tid = threadIdx.x;
  if (tid <= MAXD) hist[tid] = 0;
  __syncthreads();
  for (int n = tid; n < NN; n += 1024) {
    int c = ends[n] - starts[n]; c = c > MAXD ? MAXD : c;
    atomicAdd(&hist[c], 1);
  }
  __syncthreads();
  if (tid == 0) {
    int total = 0;
    for (int b = MAXD; b >= 0; --b) { offs[b] = total; total += hist[b]; }
  }
}

__global__ void k_scatter(const int* __restrict__ starts, const int* __restrict__ ends,
                          int* __restrict__ offs, int* __restrict__ order) {
  int n = blockIdx.x * 256 + threadIdx.x;
  if (n >= NN) return;
  int c = ends[n] - starts[n]; c = c > MAXD ? MAXD : c;
  int slot = atomicAdd(&offs[c], 1);
  order[slot] = n;  // descending-degree permutation
}

__global__ void k_nbr(const int* __restrict__ src, const int* __restrict__ trg,
                      const int* __restrict__ starts, int* __restrict__ nbr) {
  int e = blockIdx.x * 256 + threadIdx.x;
  if (e >= NE) return;
  int s = src[e];
  int pos = e - starts[s];
  if (pos < MAXD) nbr[s * MAXD + pos] = trg[e];
}

// ---- proj = X @ W_ih.T + (b_ih+b_hh), bf16 MFMA (B in AGPR, r9-passing).
// NEW layout: proj[n][d*4 + g]  (d = hidden dim 0..127, g = gate 0..3) ----
__global__ __launch_bounds__(256)
__attribute__((amdgpu_waves_per_eu(2, 2))) void k_proj(
    const float* __restrict__ x, const float* __restrict__ W_ih,
    const float* __restrict__ b_ih, const float* __restrict__ b_hh,
    short* __restrict__ proj) {
  __shared__ __align__(16) short xs[64 * HPAD];
  const int tid = threadIdx.x;
  const int wv = tid >> 6, lane = tid & 63, lq = lane >> 4, lc = lane & 15;
  const int base = blockIdx.x * 64;

  for (int idx4 = tid; idx4 < 64 * 32; idx4 += 256) {
    int row = idx4 >> 5, k4 = (idx4 & 31) << 2;
    f32x4 v = (f32x4){0.f, 0.f, 0.f, 0.f};
    if (base + row < NN) v = *(const f32x4*)&x[(base + row) * 128 + k4];
    s16x4 p; p[0] = f2bs(v[0]); p[1] = f2bs(v[1]); p[2] = f2bs(v[2]); p[3] = f2bs(v[3]);
    *(s16x4*)&xs[row * HPAD + k4] = p;
  }
  short8 wfrag[4][2][4];
#pragma unroll
  for (int g = 0; g < 4; ++g)
#pragma unroll
    for (int db = 0; db < 2; ++db)
#pragma unroll
      for (int kt = 0; kt < 4; ++kt) {
        const float* p =
            &W_ih[(g * 128 + wv * 32 + db * 16 + lc) * 128 + kt * 32 + lq * 8];
        f32x4 a = *(const f32x4*)p;
        f32x4 b = *(const f32x4*)(p + 4);
        short8 w;
        w[0] = f2bs(a[0]); w[1] = f2bs(a[1]); w[2] = f2bs(a[2]); w[3] = f2bs(a[3]);
        w[4] = f2bs(b[0]); w[5] = f2bs(b[1]); w[6] = f2bs(b[2]); w[7] = f2bs(b[3]);
        wfrag[g][db][kt] = w;
      }
  float bias_v[4][2];
#pragma unroll
  for (int g = 0; g < 4; ++g)
#pragma unroll
    for (int db = 0; db < 2; ++db) {
      int j = g * 128 + wv * 32 + db * 16 + lc;
      bias_v[g][db] = b_ih[j] + b_hh[j];
    }
  __syncthreads();

#pragma unroll
  for (int mt = 0; mt < 4; ++mt) {
    short8 afrag[4];
#pragma unroll
    for (int kt = 0; kt < 4; ++kt)
      afrag[kt] = *(const short8*)&xs[(mt * 16 + lc) * HPAD + kt * 32 + lq * 8];
    f32x4 acc[4][2];
#pragma unroll
    for (int g = 0; g < 4; ++g) {
#pragma unroll
      for (int db = 0; db < 2; ++db) {
        float b = bias_v[g][db];
        acc[g][db] = (f32x4){b, b, b, b};
      }
      mfma_dual4(afrag[0], afrag[1], afrag[2], afrag[3],
                 wfrag[g][0][0], wfrag[g][0][1], wfrag[g][0][2], wfrag[g][0][3],
                 wfrag[g][1][0], wfrag[g][1][1], wfrag[g][1][2], wfrag[g][1][3],
                 acc[g][0], acc[g][1]);
    }
#pragma unroll
    for (int r = 0; r < 4; ++r) {
      int row = base + mt * 16 + lq * 4 + r;
      if (row < NN) {
#pragma unroll
        for (int db = 0; db < 2; ++db) {
          int d = wv * 32 + db * 16 + lc;
          s16x4 w4;
          w4[0] = f2bs(acc[0][db][r]); w4[1] = f2bs(acc[1][db][r]);
          w4[2] = f2bs(acc[2][db][r]); w4[3] = f2bs(acc[3][db][r]);
          *(s16x4*)&proj[row * NG + d * 4] = w4;
        }
      }
    }
  }
}

// ---- LSTM: W_hh in LDS (no register residency -> no spill possible).
// 512 threads / 8 waves; wave w owns hidden dims [w*16,+16) of all 4 gates.
// Wave w dist-1 prefetches proj rows {2w,2w+1} as 1KB coalesced gl_lds16.
// 2 barriers/step: A = pv consumed before pbuf overwrite, B = prefetch
// drain + h_s visibility. ----
__global__ __launch_bounds__(512) void k_lstm(
    const float* __restrict__ W_hh, const short* __restrict__ proj,
    const int* __restrict__ order, const int* __restrict__ starts,
    const int* __restrict__ ends, const int* __restrict__ nbr,
    short* __restrict__ agg) {
  __shared__ __align__(16) short wlds[512 * WPAD];     // 135168 B
  __shared__ __align__(16) short h_s[2][BATCH * HPAD2];// 8448 B
  __shared__ __align__(16) short pbuf[BATCH][PROW];    // 16640 B
  __shared__ unsigned short nbr_s[BATCH][MAXD];        // 1536 B
  __shared__ int nodes_s[BATCH];
  __shared__ int cnts_s[BATCH];

  const int tid = threadIdx.x;   // 0..511
  const int w = tid >> 6;        // wave 0..7
  const int lane = tid & 63;
  const int lq = lane >> 4, lc = lane & 15;
  const int batch = blockIdx.x;

  if (tid < BATCH) {
    int gidx = batch * BATCH + tid;
    int node = 0, c = 0;
    if (gidx < NN) {
      node = order[gidx];
      c = ends[node] - starts[node]; c = c > MAXD ? MAXD : c;
    }
    nodes_s[tid] = node;
    cnts_s[tid] = c;
  }
  for (int idx = tid; idx < BATCH * HPAD2 / 2; idx += 512)
    ((int*)h_s[0])[idx] = 0;
  __syncthreads();
  // stage W_hh (bf16) + neighbor lists
  for (int i = tid; i < 512 * 32; i += 512) {
    int j = i >> 5, k4 = (i & 31) << 2;
    f32x4 v = *(const f32x4*)&W_hh[j * 128 + k4];
    s16x4 p; p[0] = f2bs(v[0]); p[1] = f2bs(v[1]); p[2] = f2bs(v[2]); p[3] = f2bs(v[3]);
    *(s16x4*)&wlds[j * WPAD + k4] = p;
  }
  for (int idx = tid; idx < BATCH * MAXD; idx += 512) {
    int m = idx / MAXD, p = idx - m * MAXD;
    nbr_s[m][p] = (unsigned short)nbr[nodes_s[m] * MAXD + p];
  }
  __syncthreads();
  const int T = cnts_s[0];  // descending sort -> batch max

  const int r0 = 2 * w, r1 = 2 * w + 1;  // rows this wave gathers
  const int c0 = cnts_s[r0], c1 = cnts_s[r1];
  int cpk = 0;  // packed per-lane row counts (rows lq*4+r)
#pragma unroll
  for (int r = 0; r < 4; ++r) cpk |= cnts_s[lq * 4 + r] << (r * 8);

  f32x4 c_v = (f32x4){0.f, 0.f, 0.f, 0.f};
  s16x4 hvp = (s16x4){0, 0, 0, 0};

  if (T > 0) {  // prologue gather for t=0
    int n0 = (0 < c0) ? (int)nbr_s[r0][0] : 0;
    int n1 = (0 < c1) ? (int)nbr_s[r1][0] : 0;
    gl_lds16(&proj[n0 * NG + lane * 8], &pbuf[r0][0]);
    gl_lds16(&proj[n1 * NG + lane * 8], &pbuf[r1][0]);
  }
  __syncthreads();  // prologue prefetch drained (vmcnt) before t=0 reads

  const int hd = w * 16 + lc;  // this lane's hidden dim
  for (int t = 0; t < T; ++t) {
    // consume this step's proj slices: row lq*4+r, dims hd, 4 gates (8B)
    s16x4 pv[4];
#pragma unroll
    for (int r = 0; r < 4; ++r)
      pv[r] = *(const s16x4*)&pbuf[lq * 4 + r][hd * 4];
    __syncthreads();  // barrier A: all pv reads done before overwrite
    const int tn = t + 1;
    if (tn < T) {  // prefetch t+1 (coalesced 1KB per row)
      const int ts = tn < MAXD ? tn : 0;
      int n0 = (tn < c0) ? (int)nbr_s[r0][ts] : 0;
      int n1 = (tn < c1) ? (int)nbr_s[r1][ts] : 0;
      gl_lds16(&proj[n0 * NG + lane * 8], &pbuf[r0][0]);
      gl_lds16(&proj[n1 * NG + lane * 8], &pbuf[r1][0]);
    }
    const short* hb = h_s[t & 1];
    short* hw = h_s[tn & 1];
    short8 afrag[4];
#pragma unroll
    for (int kt = 0; kt < 4; ++kt)
      afrag[kt] = *(const short8*)&hb[lc * HPAD2 + kt * 32 + lq * 8];
    f32x4 acc[4];
#pragma unroll
    for (int g = 0; g < 4; ++g) {
      acc[g][0] = bs2f(pv[0][g]); acc[g][1] = bs2f(pv[1][g]);
      acc[g][2] = bs2f(pv[2][g]); acc[g][3] = bs2f(pv[3][g]);
      short8 bf[4];
#pragma unroll
      for (int kt = 0; kt < 4; ++kt)
        bf[kt] = *(const short8*)&wlds[(g * 128 + hd) * WPAD + kt * 32 + lq * 8];
#pragma unroll
      for (int kt = 0; kt < 4; ++kt)
        acc[g] = __builtin_amdgcn_mfma_f32_16x16x32_bf16(afrag[kt], bf[kt],
                                                         acc[g], 0, 0, 0);
    }
#pragma unroll
    for (int r = 0; r < 4; ++r) {
      float iv = sigf(acc[0][r]);
      float fv = sigf(acc[1][r]);
      float gv = tanh_(acc[2][r]);
      float ov = sigf(acc[3][r]);
      float c2 = fv * c_v[r] + iv * gv;
      float h2 = ov * tanh_(c2);
      if (t < ((cpk >> (r * 8)) & 255)) {
        c_v[r] = c2;
        hvp[r] = f2bs(h2);
      }
    }
#pragma unroll
    for (int r = 0; r < 4; ++r)
      hw[(lq * 4 + r) * HPAD2 + hd] = hvp[r];  // new or carried h
    __syncthreads();  // barrier B: prefetch drained + h writes visible
  }
  const short* hf = h_s[T & 1];
  for (int idx = tid; idx < BATCH * 128; idx += 512) {
    int m = idx >> 7, d = idx & 127;
    if (batch * BATCH + m < NN) agg[nodes_s[m] * 128 + d] = hf[m * HPAD2 + d];
  }
}

// ---- out = [x | h] @ W_out, bf16 MFMA ----
__global__ __launch_bounds__(256, 2) void k_out(
    const float* __restrict__ x, const short* __restrict__ agg,
    const float* __restrict__ Wout, float* __restrict__ out) {
  __shared__ __align__(16) short xs[64 * 272];
  const int tid = threadIdx.x;
  const int wv = tid >> 6, lane = tid & 63, lq = lane >> 4, lc = lane & 15;
  const int base = blockIdx.x * 64;

  for (int idx4 = tid; idx4 < 64 * 32; idx4 += 256) {
    int row = idx4 >> 5, k4 = (idx4 & 31) << 2;
    f32x4 v = (f32x4){0.f, 0.f, 0.f, 0.f};
    if (base + row < NN) v = *(const f32x4*)&x[(base + row) * 128 + k4];
    s16x4 p; p[0] = f2bs(v[0]); p[1] = f2bs(v[1]); p[2] = f2bs(v[2]); p[3] = f2bs(v[3]);
    *(s16x4*)&xs[row * 272 + k4] = p;
    s16x4 a = (s16x4){0, 0, 0, 0};
    if (base + row < NN) a = *(const s16x4*)&agg[(base + row) * 128 + k4];
    *(s16x4*)&xs[row * 272 + 128 + k4] = a;
  }
  short8 wf[2][8];
#pragma unroll
  for (int db = 0; db < 2; ++db)
#pragma unroll
    for (int kt = 0; kt < 8; ++kt) {
      short8 w;
#pragma unroll
      for (int jj = 0; jj < 8; ++jj)
        w[jj] = f2bs(Wout[(kt * 32 + lq * 8 + jj) * 128 + wv * 32 + db * 16 + lc]);
      wf[db][kt] = w;
    }
  __syncthreads();

#pragma unroll
  for (int mt = 0; mt < 4; ++mt) {
    short8 afrag[8];
#pragma unroll
    for (int kt = 0; kt < 8; ++kt)
      afrag[kt] = *(const short8*)&xs[(mt * 16 + lc) * 272 + kt * 32 + lq * 8];
    f32x4 acc[2];
#pragma unroll
    for (int db = 0; db < 2; ++db) {
      acc[db] = (f32x4){0.f, 0.f, 0.f, 0.f};
#pragma unroll
      for (int kt = 0; kt < 8; ++kt)
        acc[db] = __builtin_amdgcn_mfma_f32_16x16x32_bf16(
            afrag[kt], wf[db][kt], acc[db], 0, 0, 0);
    }
#pragma unroll
    for (int db = 0; db < 2; ++db)
#pragma unroll
      for (int r = 0; r < 4; ++r) {
        int row = base + mt * 16 + lq * 4 + r;
        if (row < NN)
          out[row * 128 + wv * 32 + db * 16 + lc] = acc[db][r];
      }
  }
}

extern "C" void kernel_launch(void* const* d_in, const int* in_sizes, int n_in,
                              void* d_out, int out_size, void* d_ws,
                              size_t ws_size, hipStream_t stream) {
  (void)in_sizes; (void)n_in; (void)out_size; (void)ws_size;
  const float* x     = (const float*)d_in[0];
  const float* W_ih  = (const float*)d_in[1];
  const float* W_hh  = (const float*)d_in[2];
  const float* b_ih  = (const float*)d_in[3];
  const float* b_hh  = (const float*)d_in[4];
  const float* W_out = (const float*)d_in[5];
  const int*   esrc  = (const int*)d_in[6];
  const int*   etrg  = (const int*)d_in[7];
  float* out = (float*)d_out;
  char* ws = (char*)d_ws;

  int*   starts = (int*)(ws + 0);          // 120000 B
  int*   ends   = (int*)(ws + 120064);     // 120000 B
  int*   offs   = (int*)(ws + 240128);     // 196 B
  int*   order  = (int*)(ws + 240384);     // 120000 B
  int*   nbr    = (int*)(ws + 360448);     // 5,760,000 B
  short* proj   = (short*)(ws + 6382848);  // 30,720,000 B (bf16, d*4+g layout)
  short* agg    = (short*)(ws + 37102848); // 7,680,000 B (bf16)

  (void)hipMemsetAsync(d_ws, 0, 240128, stream);  // starts + ends

  k_edges  <<<1875, 256, 0, stream>>>(esrc, starts, ends);
  k_hs     <<<1, 1024, 0, stream>>>(starts, ends, offs);
  k_scatter<<<118, 256, 0, stream>>>(starts, ends, offs, order);
  k_nbr    <<<1875, 256, 0, stream>>>(esrc, etrg, starts, nbr);
  k_proj   <<<NGB, 256, 0, stream>>>(x, W_ih, b_ih, b_hh, proj);
  k_lstm   <<<NB, 512, 0, stream>>>(W_hh, proj, order, starts, ends, nbr, agg);
  k_out    <<<NGB, 256, 0, stream>>>(x, agg, W_out, out);
}

// Round 11
// 418.366 us; speedup vs baseline: 1.3765x; 1.3765x over previous
//
#include <hip/hip_runtime.h>

#define NN 30000
#define NE 480000
#define NG 512
#define MAXD 48
#define BATCH 32
#define NB 938    // ceil(30000/32)
#define HPAD 136  // h_s row stride (shorts); 136 (not 144) -> LDS 53504B -> 3 blocks/CU
#define XPAD 144  // k_proj x-stage row stride
#define NGB 469   // ceil(30000/64) for the 64-row GEMM kernels

typedef __attribute__((ext_vector_type(8))) short short8;
typedef __attribute__((ext_vector_type(4))) short s16x4;
typedef __attribute__((ext_vector_type(4))) float f32x4;

static __device__ __forceinline__ short f2bs(float f) {
  unsigned u = __builtin_bit_cast(unsigned, f);
  u = (u + 0x7fffu + ((u >> 16) & 1u)) >> 16;
  return (short)u;
}
static __device__ __forceinline__ float bs2f(short s) {
  unsigned u = ((unsigned)(unsigned short)s) << 16;
  return __builtin_bit_cast(float, u);
}
static __device__ __forceinline__ float sigf(float x) {
  return __builtin_amdgcn_rcpf(1.0f + __expf(-x));
}
static __device__ __forceinline__ float tanh_(float x) {
  return 1.0f - 2.0f * __builtin_amdgcn_rcpf(1.0f + __expf(2.0f * x));
}
// async 16B-per-lane gather into LDS: dest = ldsbase + lane*16
static __device__ __forceinline__ void gl_lds16(const short* g, short* l) {
  __builtin_amdgcn_global_load_lds(
      (const __attribute__((address_space(1))) void*)g,
      (__attribute__((address_space(3))) void*)l, 16, 0, 0);
}

// ---- prep: segment starts/ends via boundary detection (src sorted) ----
__global__ void k_edges(const int* __restrict__ src, int* __restrict__ starts,
                        int* __restrict__ ends) {
  int e = blockIdx.x * 256 + threadIdx.x;
  if (e >= NE) return;
  int s = src[e];
  if (e == 0 || src[e - 1] != s) starts[s] = e;
  if (e == NE - 1 || src[e + 1] != s) ends[s] = e + 1;
}

__global__ void k_hs(const int* __restrict__ starts, const int* __restrict__ ends,
                     int* __restrict__ offs) {
  __shared__ int hist[MAXD + 1];
  int tid = threadIdx.x;
  if (tid <= MAXD) hist[tid] = 0;
  __syncthreads();
  for (int n = tid; n < NN; n += 1024) {
    int c = ends[n] - starts[n]; c = c > MAXD ? MAXD : c;
    atomicAdd(&hist[c], 1);
  }
  __syncthreads();
  if (tid == 0) {
    int total = 0;
    for (int b = MAXD; b >= 0; --b) { offs[b] = total; total += hist[b]; }
  }
}

__global__ void k_scatter(const int* __restrict__ starts, const int* __restrict__ ends,
                          int* __restrict__ offs, int* __restrict__ order) {
  int n = blockIdx.x * 256 + threadIdx.x;
  if (n >= NN) return;
  int c = ends[n] - starts[n]; c = c > MAXD ? MAXD : c;
  int slot = atomicAdd(&offs[c], 1);
  order[slot] = n;  // descending-degree permutation
}

__global__ void k_nbr(const int* __restrict__ src, const int* __restrict__ trg,
                      const int* __restrict__ starts, int* __restrict__ nbr) {
  int e = blockIdx.x * 256 + threadIdx.x;
  if (e >= NE) return;
  int s = src[e];
  int pos = e - starts[s];
  if (pos < MAXD) nbr[s * MAXD + pos] = trg[e];
}

// ---- proj = X @ W_ih.T + (b_ih+b_hh), bf16 MFMA.
// Layout (same as r7): j = g*128 + wv*32 + db*16 + lc -> pos=(wv*16+lc)*8+g*2+db.
// Gate-OUTER loop: only one gate's wfrag (32 regs) live at a time -> no spill
// at the 128-reg 2-wave cap (the 128-reg all-gates wfrag was spilling). ----
__global__ __launch_bounds__(256, 2) void k_proj(
    const float* __restrict__ x, const float* __restrict__ W_ih,
    const float* __restrict__ b_ih, const float* __restrict__ b_hh,
    short* __restrict__ proj) {
  __shared__ __align__(16) short xs[64 * XPAD];
  const int tid = threadIdx.x;
  const int wv = tid >> 6, lane = tid & 63, lq = lane >> 4, lc = lane & 15;
  const int base = blockIdx.x * 64;

  for (int idx4 = tid; idx4 < 64 * 32; idx4 += 256) {
    int row = idx4 >> 5, k4 = (idx4 & 31) << 2;
    f32x4 v = (f32x4){0.f, 0.f, 0.f, 0.f};
    if (base + row < NN) v = *(const f32x4*)&x[(base + row) * 128 + k4];
    s16x4 p; p[0] = f2bs(v[0]); p[1] = f2bs(v[1]); p[2] = f2bs(v[2]); p[3] = f2bs(v[3]);
    *(s16x4*)&xs[row * XPAD + k4] = p;
  }
  __syncthreads();

  const int pbase = (wv * 16 + lc) * 8;
#pragma unroll
  for (int g = 0; g < 4; ++g) {
    short8 wfrag[2][4];
#pragma unroll
    for (int db = 0; db < 2; ++db)
#pragma unroll
      for (int kt = 0; kt < 4; ++kt) {
        const float* p =
            &W_ih[(g * 128 + wv * 32 + db * 16 + lc) * 128 + kt * 32 + lq * 8];
        f32x4 a = *(const f32x4*)p;
        f32x4 b = *(const f32x4*)(p + 4);
        short8 w;
        w[0] = f2bs(a[0]); w[1] = f2bs(a[1]); w[2] = f2bs(a[2]); w[3] = f2bs(a[3]);
        w[4] = f2bs(b[0]); w[5] = f2bs(b[1]); w[6] = f2bs(b[2]); w[7] = f2bs(b[3]);
        wfrag[db][kt] = w;
      }
    float bias0, bias1;
    {
      int j0 = g * 128 + wv * 32 + lc;
      bias0 = b_ih[j0] + b_hh[j0];
      bias1 = b_ih[j0 + 16] + b_hh[j0 + 16];
    }
#pragma unroll
    for (int mt = 0; mt < 4; ++mt) {
      short8 afrag[4];
#pragma unroll
      for (int kt = 0; kt < 4; ++kt)
        afrag[kt] = *(const short8*)&xs[(mt * 16 + lc) * XPAD + kt * 32 + lq * 8];
      f32x4 acc[2];
      acc[0] = (f32x4){bias0, bias0, bias0, bias0};
      acc[1] = (f32x4){bias1, bias1, bias1, bias1};
#pragma unroll
      for (int db = 0; db < 2; ++db)
#pragma unroll
        for (int kt = 0; kt < 4; ++kt)
          acc[db] = __builtin_amdgcn_mfma_f32_16x16x32_bf16(
              afrag[kt], wfrag[db][kt], acc[db], 0, 0, 0);
#pragma unroll
      for (int r = 0; r < 4; ++r) {
        int row = base + mt * 16 + lq * 4 + r;
        if (row < NN) {
          unsigned v = (unsigned)(unsigned short)f2bs(acc[0][r]) |
                       ((unsigned)(unsigned short)f2bs(acc[1][r]) << 16);
          *(unsigned*)&proj[row * NG + pbase + g * 2] = v;  // 4B: (g,db0),(g,db1)
        }
      }
    }
  }
}

// ---- LSTM: r7's structure verbatim (best known: 217us), HPAD 144->136 to fit
// LDS in 160/3 KB -> 3 blocks/CU (12 waves) for +50% gather concurrency.
// W_hh B-frags register-resident (spills ~105MB at the 128-cap -- accepted:
// measured cheaper than every no-spill alternative at equal wave count). ----
__global__ __launch_bounds__(256, 2) void k_lstm(
    const float* __restrict__ W_hh, const short* __restrict__ proj,
    const int* __restrict__ order, const int* __restrict__ starts,
    const int* __restrict__ ends, const int* __restrict__ nbr,
    short* __restrict__ agg) {
  __shared__ __align__(16) short h_s[2][BATCH * HPAD];   // 17408 B
  __shared__ __align__(16) short pbuf[4][8][64 * 8];     // 32768 B, wave-private
  __shared__ unsigned short nbr_s[BATCH][MAXD];          // 3072 B
  __shared__ int nodes_s[BATCH];                         // 128 B
  __shared__ int cnts_s[BATCH];                          // 128 B -> 53504 B total

  const int tid = threadIdx.x;
  const int wv = tid >> 6, lane = tid & 63, lq = lane >> 4, lc = lane & 15;

  short8 wfrag[4][2][4];
#pragma unroll
  for (int g = 0; g < 4; ++g)
#pragma unroll
    for (int db = 0; db < 2; ++db)
#pragma unroll
      for (int kt = 0; kt < 4; ++kt) {
        const float* p =
            &W_hh[(g * 128 + wv * 32 + db * 16 + lc) * 128 + kt * 32 + lq * 8];
        f32x4 a = *(const f32x4*)p;
        f32x4 b = *(const f32x4*)(p + 4);
        short8 w;
        w[0] = f2bs(a[0]); w[1] = f2bs(a[1]); w[2] = f2bs(a[2]); w[3] = f2bs(a[3]);
        w[4] = f2bs(b[0]); w[5] = f2bs(b[1]); w[6] = f2bs(b[2]); w[7] = f2bs(b[3]);
        wfrag[g][db][kt] = w;
      }

  const int batch = blockIdx.x;
  if (tid < BATCH) {
    int gidx = batch * BATCH + tid;
    int node = 0, c = 0;
    if (gidx < NN) {
      node = order[gidx];
      c = ends[node] - starts[node]; c = c > MAXD ? MAXD : c;
    }
    nodes_s[tid] = node;
    cnts_s[tid] = c;
  }
  __syncthreads();
  for (int idx = tid; idx < BATCH * HPAD / 2; idx += 256)
    ((int*)h_s[0])[idx] = 0;
  for (int idx = tid; idx < BATCH * MAXD; idx += 256) {
    int m = idx / MAXD, p = idx - m * MAXD;
    nbr_s[m][p] = (unsigned short)nbr[nodes_s[m] * MAXD + p];
  }
  __syncthreads();
  const int T = cnts_s[0];  // descending sort -> batch max

  // counts packed 4-per-int (each <= 48 fits in 8 bits)
  int cp[2];
#pragma unroll
  for (int mt = 0; mt < 2; ++mt) {
    int p = 0;
#pragma unroll
    for (int r = 0; r < 4; ++r) p |= cnts_s[mt * 16 + lq * 4 + r] << (r * 8);
    cp[mt] = p;
  }

  float c_v[2][2][4];
  s16x4 hvp[2][2];  // last-written h (bf16) for copy-forward of frozen rows
#pragma unroll
  for (int mt = 0; mt < 2; ++mt)
#pragma unroll
    for (int db = 0; db < 2; ++db) {
#pragma unroll
      for (int r = 0; r < 4; ++r) c_v[mt][db][r] = 0.0f;
      hvp[mt][db] = (s16x4){0, 0, 0, 0};
    }

  const int pcol = (wv * 16 + lc) * 8;
  if (T > 0) {  // prologue: async-gather t=0 slices into pbuf
#pragma unroll
    for (int mt = 0; mt < 2; ++mt)
#pragma unroll
      for (int r = 0; r < 4; ++r) {
        int m = mt * 16 + lq * 4 + r;
        int nb_i = (0 < ((cp[mt] >> (r * 8)) & 255)) ? (int)nbr_s[m][0] : 0;
        gl_lds16(&proj[nb_i * NG + pcol], &pbuf[wv][mt * 4 + r][0]);
      }
  }

  for (int t = 0; t < T; ++t) {
    __syncthreads();  // drains prefetch (vmcnt) + makes h writes visible
    const short* hb = h_s[t & 1];
    short* hw = h_s[(t + 1) & 1];
    const int tn = t + 1;
    const int ts = tn < MAXD ? tn : 0;
#pragma unroll
    for (int mt = 0; mt < 2; ++mt) {
      // consume this step's gathered slices (wave-private slots)
      short8 pv[4];
#pragma unroll
      for (int r = 0; r < 4; ++r)
        pv[r] = *(const short8*)&pbuf[wv][mt * 4 + r][lane * 8];
      f32x4 acc[4][2];
#pragma unroll
      for (int g = 0; g < 4; ++g)
#pragma unroll
        for (int db = 0; db < 2; ++db)
#pragma unroll
          for (int r = 0; r < 4; ++r)
            acc[g][db][r] = bs2f(pv[r][g * 2 + db]);  // x-part + bias
      __builtin_amdgcn_sched_barrier(0);  // pv fully consumed before overwrite
      if (tn < T) {  // prefetch t+1 into the same (now free) slots
#pragma unroll
        for (int r = 0; r < 4; ++r) {
          int m = mt * 16 + lq * 4 + r;
          int nb_i = (tn < ((cp[mt] >> (r * 8)) & 255)) ? (int)nbr_s[m][ts] : 0;
          gl_lds16(&proj[nb_i * NG + pcol], &pbuf[wv][mt * 4 + r][0]);
        }
      }
      __builtin_amdgcn_sched_barrier(0);  // keep prefetch issue early
      short8 afrag[4];
#pragma unroll
      for (int kt = 0; kt < 4; ++kt)
        afrag[kt] = *(const short8*)&hb[(mt * 16 + lc) * HPAD + kt * 32 + lq * 8];
#pragma unroll
      for (int g = 0; g < 4; ++g)
#pragma unroll
        for (int db = 0; db < 2; ++db)
#pragma unroll
          for (int kt = 0; kt < 4; ++kt)
            acc[g][db] = __builtin_amdgcn_mfma_f32_16x16x32_bf16(
                afrag[kt], wfrag[g][db][kt], acc[g][db], 0, 0, 0);
#pragma unroll
      for (int db = 0; db < 2; ++db)
#pragma unroll
        for (int r = 0; r < 4; ++r) {
          float iv = sigf(acc[0][db][r]);
          float fv = sigf(acc[1][db][r]);
          float gv = tanh_(acc[2][db][r]);
          float ov = sigf(acc[3][db][r]);
          float c2 = fv * c_v[mt][db][r] + iv * gv;
          float h2 = ov * tanh_(c2);
          if (t < ((cp[mt] >> (r * 8)) & 255)) {
            c_v[mt][db][r] = c2;
            hvp[mt][db][r] = f2bs(h2);
          }
        }
      // unconditional write of (new or carried) h into the other buffer
#pragma unroll
      for (int db = 0; db < 2; ++db)
#pragma unroll
        for (int r = 0; r < 4; ++r)
          hw[(mt * 16 + lq * 4 + r) * HPAD + wv * 32 + db * 16 + lc] =
              hvp[mt][db][r];
    }
  }
  __syncthreads();  // last step's h writes visible
  const short* hf = h_s[T & 1];
  for (int idx = tid; idx < BATCH * 128; idx += 256) {
    int m = idx >> 7, d = idx & 127;
    if (batch * BATCH + m < NN) agg[nodes_s[m] * 128 + d] = hf[m * HPAD + d];
  }
}

// ---- out = [x | h] @ W_out, bf16 MFMA ----
__global__ __launch_bounds__(256, 2) void k_out(
    const float* __restrict__ x, const short* __restrict__ agg,
    const float* __restrict__ Wout, float* __restrict__ out) {
  __shared__ __align__(16) short xs[64 * 272];
  const int tid = threadIdx.x;
  const int wv = tid >> 6, lane = tid & 63, lq = lane >> 4, lc = lane & 15;
  const int base = blockIdx.x * 64;

  for (int idx4 = tid; idx4 < 64 * 32; idx4 += 256) {
    int row = idx4 >> 5, k4 = (idx4 & 31) << 2;
    f32x4 v = (f32x4){0.f, 0.f, 0.f, 0.f};
    if (base + row < NN) v = *(const f32x4*)&x[(base + row) * 128 + k4];
    s16x4 p; p[0] = f2bs(v[0]); p[1] = f2bs(v[1]); p[2] = f2bs(v[2]); p[3] = f2bs(v[3]);
    *(s16x4*)&xs[row * 272 + k4] = p;
    s16x4 a = (s16x4){0, 0, 0, 0};
    if (base + row < NN) a = *(const s16x4*)&agg[(base + row) * 128 + k4];
    *(s16x4*)&xs[row * 272 + 128 + k4] = a;
  }
  short8 wf[2][8];
#pragma unroll
  for (int db = 0; db < 2; ++db)
#pragma unroll
    for (int kt = 0; kt < 8; ++kt) {
      short8 w;
#pragma unroll
      for (int jj = 0; jj < 8; ++jj)
        w[jj] = f2bs(Wout[(kt * 32 + lq * 8 + jj) * 128 + wv * 32 + db * 16 + lc]);
      wf[db][kt] = w;
    }
  __syncthreads();

#pragma unroll
  for (int mt = 0; mt < 4; ++mt) {
    short8 afrag[8];
#pragma unroll
    for (int kt = 0; kt < 8; ++kt)
      afrag[kt] = *(const short8*)&xs[(mt * 16 + lc) * 272 + kt * 32 + lq * 8];
    f32x4 acc[2];
#pragma unroll
    for (int db = 0; db < 2; ++db) {
      acc[db] = (f32x4){0.f, 0.f, 0.f, 0.f};
#pragma unroll
      for (int kt = 0; kt < 8; ++kt)
        acc[db] = __builtin_amdgcn_mfma_f32_16x16x32_bf16(
            afrag[kt], wf[db][kt], acc[db], 0, 0, 0);
    }
#pragma unroll
    for (int db = 0; db < 2; ++db)
#pragma unroll
      for (int r = 0; r < 4; ++r) {
        int row = base + mt * 16 + lq * 4 + r;
        if (row < NN)
          out[row * 128 + wv * 32 + db * 16 + lc] = acc[db][r];
      }
  }
}

extern "C" void kernel_launch(void* const* d_in, const int* in_sizes, int n_in,
                              void* d_out, int out_size, void* d_ws,
                              size_t ws_size, hipStream_t stream) {
  (void)in_sizes; (void)n_in; (void)out_size; (void)ws_size;
  const float* x     = (const float*)d_in[0];
  const float* W_ih  = (const float*)d_in[1];
  const float* W_hh  = (const float*)d_in[2];
  const float* b_ih  = (const float*)d_in[3];
  const float* b_hh  = (const float*)d_in[4];
  const float* W_out = (const float*)d_in[5];
  const int*   esrc  = (const int*)d_in[6];
  const int*   etrg  = (const int*)d_in[7];
  float* out = (float*)d_out;
  char* ws = (char*)d_ws;

  int*   starts = (int*)(ws + 0);          // 120000 B
  int*   ends   = (int*)(ws + 120064);     // 120000 B
  int*   offs   = (int*)(ws + 240128);     // 196 B
  int*   order  = (int*)(ws + 240384);     // 120000 B
  int*   nbr    = (int*)(ws + 360448);     // 5,760,000 B
  short* proj   = (short*)(ws + 6382848);  // 30,720,000 B (bf16, permuted cols)
  short* agg    = (short*)(ws + 37102848); // 7,680,000 B (bf16)

  (void)hipMemsetAsync(d_ws, 0, 240128, stream);  // starts + ends

  k_edges  <<<1875, 256, 0, stream>>>(esrc, starts, ends);
  k_hs     <<<1, 1024, 0, stream>>>(starts, ends, offs);
  k_scatter<<<118, 256, 0, stream>>>(starts, ends, offs, order);
  k_nbr    <<<1875, 256, 0, stream>>>(esrc, etrg, starts, nbr);
  k_proj   <<<NGB, 256, 0, stream>>>(x, W_ih, b_ih, b_hh, proj);
  k_lstm   <<<NB, 256, 0, stream>>>(W_hh, proj, order, starts, ends, nbr, agg);
  k_out    <<<NGB, 256, 0, stream>>>(x, agg, W_out, out);
}

// Round 12
// 418.034 us; speedup vs baseline: 1.3776x; 1.0008x over previous
//
#include <hip/hip_runtime.h>

#define NN 30000
#define NE 480000
#define NG 512
#define MAXD 48
#define BATCH 32
#define NB 938    // ceil(30000/32)
#define HPAD 136  // h_s row stride (shorts)
#define XPAD 144  // k_proj x-stage row stride
#define NGB 469   // ceil(30000/64) for the 64-row GEMM kernels

typedef __attribute__((ext_vector_type(8))) short short8;
typedef __attribute__((ext_vector_type(4))) short s16x4;
typedef __attribute__((ext_vector_type(4))) float f32x4;

static __device__ __forceinline__ short f2bs(float f) {
  unsigned u = __builtin_bit_cast(unsigned, f);
  u = (u + 0x7fffu + ((u >> 16) & 1u)) >> 16;
  return (short)u;
}
static __device__ __forceinline__ float bs2f(short s) {
  unsigned u = ((unsigned)(unsigned short)s) << 16;
  return __builtin_bit_cast(float, u);
}
static __device__ __forceinline__ float sigf(float x) {
  return __builtin_amdgcn_rcpf(1.0f + __expf(-x));
}
static __device__ __forceinline__ float tanh_(float x) {
  return 1.0f - 2.0f * __builtin_amdgcn_rcpf(1.0f + __expf(2.0f * x));
}
// async 16B-per-lane gather into LDS: dest = ldsbase + lane*16
static __device__ __forceinline__ void gl_lds16(const short* g, short* l) {
  __builtin_amdgcn_global_load_lds(
      (const __attribute__((address_space(1))) void*)g,
      (__attribute__((address_space(3))) void*)l, 16, 0, 0);
}

// ---- prep: segment starts/ends via boundary detection (src sorted) ----
__global__ void k_edges(const int* __restrict__ src, int* __restrict__ starts,
                        int* __restrict__ ends) {
  int e = blockIdx.x * 256 + threadIdx.x;
  if (e >= NE) return;
  int s = src[e];
  if (e == 0 || src[e - 1] != s) starts[s] = e;
  if (e == NE - 1 || src[e + 1] != s) ends[s] = e + 1;
}

__global__ void k_hs(const int* __restrict__ starts, const int* __restrict__ ends,
                     int* __restrict__ offs) {
  __shared__ int hist[MAXD + 1];
  int tid = threadIdx.x;
  if (tid <= MAXD) hist[tid] = 0;
  __syncthreads();
  for (int n = tid; n < NN; n += 1024) {
    int c = ends[n] - starts[n]; c = c > MAXD ? MAXD : c;
    atomicAdd(&hist[c], 1);
  }
  __syncthreads();
  if (tid == 0) {
    int total = 0;
    for (int b = MAXD; b >= 0; --b) { offs[b] = total; total += hist[b]; }
  }
}

__global__ void k_scatter(const int* __restrict__ starts, const int* __restrict__ ends,
                          int* __restrict__ offs, int* __restrict__ order) {
  int n = blockIdx.x * 256 + threadIdx.x;
  if (n >= NN) return;
  int c = ends[n] - starts[n]; c = c > MAXD ? MAXD : c;
  int slot = atomicAdd(&offs[c], 1);
  order[slot] = n;  // descending-degree permutation
}

__global__ void k_nbr(const int* __restrict__ src, const int* __restrict__ trg,
                      const int* __restrict__ starts, int* __restrict__ nbr) {
  int e = blockIdx.x * 256 + threadIdx.x;
  if (e >= NE) return;
  int s = src[e];
  int pos = e - starts[s];
  if (pos < MAXD) nbr[s * MAXD + pos] = trg[e];
}

// ---- proj = X @ W_ih.T + (b_ih+b_hh), bf16 MFMA.
// Layout: j = g*128 + wv*32 + db*16 + lc -> pos=(wv*16+lc)*8+g*2+db.
// Gate loop is unroll-1 SEQUENTIAL: r11's full unroll let the scheduler hoist
// all 4 gates' wfrag loads -> 128-reg live set -> ~105MB scratch spill. ----
__global__ __launch_bounds__(256, 2) void k_proj(
    const float* __restrict__ x, const float* __restrict__ W_ih,
    const float* __restrict__ b_ih, const float* __restrict__ b_hh,
    short* __restrict__ proj) {
  __shared__ __align__(16) short xs[64 * XPAD];
  const int tid = threadIdx.x;
  const int wv = tid >> 6, lane = tid & 63, lq = lane >> 4, lc = lane & 15;
  const int base = blockIdx.x * 64;

  for (int idx4 = tid; idx4 < 64 * 32; idx4 += 256) {
    int row = idx4 >> 5, k4 = (idx4 & 31) << 2;
    f32x4 v = (f32x4){0.f, 0.f, 0.f, 0.f};
    if (base + row < NN) v = *(const f32x4*)&x[(base + row) * 128 + k4];
    s16x4 p; p[0] = f2bs(v[0]); p[1] = f2bs(v[1]); p[2] = f2bs(v[2]); p[3] = f2bs(v[3]);
    *(s16x4*)&xs[row * XPAD + k4] = p;
  }
  __syncthreads();

  const int pbase = (wv * 16 + lc) * 8;
#pragma unroll 1
  for (int g = 0; g < 4; ++g) {
    short8 wfrag[2][4];
#pragma unroll
    for (int db = 0; db < 2; ++db)
#pragma unroll
      for (int kt = 0; kt < 4; ++kt) {
        const float* p =
            &W_ih[(g * 128 + wv * 32 + db * 16 + lc) * 128 + kt * 32 + lq * 8];
        f32x4 a = *(const f32x4*)p;
        f32x4 b = *(const f32x4*)(p + 4);
        short8 w;
        w[0] = f2bs(a[0]); w[1] = f2bs(a[1]); w[2] = f2bs(a[2]); w[3] = f2bs(a[3]);
        w[4] = f2bs(b[0]); w[5] = f2bs(b[1]); w[6] = f2bs(b[2]); w[7] = f2bs(b[3]);
        wfrag[db][kt] = w;
      }
    float bias0, bias1;
    {
      int j0 = g * 128 + wv * 32 + lc;
      bias0 = b_ih[j0] + b_hh[j0];
      bias1 = b_ih[j0 + 16] + b_hh[j0 + 16];
    }
#pragma unroll
    for (int mt = 0; mt < 4; ++mt) {
      short8 afrag[4];
#pragma unroll
      for (int kt = 0; kt < 4; ++kt)
        afrag[kt] = *(const short8*)&xs[(mt * 16 + lc) * XPAD + kt * 32 + lq * 8];
      f32x4 acc[2];
      acc[0] = (f32x4){bias0, bias0, bias0, bias0};
      acc[1] = (f32x4){bias1, bias1, bias1, bias1};
#pragma unroll
      for (int db = 0; db < 2; ++db)
#pragma unroll
        for (int kt = 0; kt < 4; ++kt)
          acc[db] = __builtin_amdgcn_mfma_f32_16x16x32_bf16(
              afrag[kt], wfrag[db][kt], acc[db], 0, 0, 0);
#pragma unroll
      for (int r = 0; r < 4; ++r) {
        int row = base + mt * 16 + lq * 4 + r;
        if (row < NN) {
          unsigned v = (unsigned)(unsigned short)f2bs(acc[0][r]) |
                       ((unsigned)(unsigned short)f2bs(acc[1][r]) << 16);
          *(unsigned*)&proj[row * NG + pbase + g * 2] = v;  // 4B: (g,db0),(g,db1)
        }
      }
    }
  }
}

// ---- LSTM: r11 verbatim (215us plateau: register file caps 8 waves/CU;
// W_hh-resident spill ~105MB accepted as cheapest measured variant). ----
__global__ __launch_bounds__(256, 2) void k_lstm(
    const float* __restrict__ W_hh, const short* __restrict__ proj,
    const int* __restrict__ order, const int* __restrict__ starts,
    const int* __restrict__ ends, const int* __restrict__ nbr,
    short* __restrict__ agg) {
  __shared__ __align__(16) short h_s[2][BATCH * HPAD];   // 17408 B
  __shared__ __align__(16) short pbuf[4][8][64 * 8];     // 32768 B, wave-private
  __shared__ unsigned short nbr_s[BATCH][MAXD];          // 3072 B
  __shared__ int nodes_s[BATCH];
  __shared__ int cnts_s[BATCH];

  const int tid = threadIdx.x;
  const int wv = tid >> 6, lane = tid & 63, lq = lane >> 4, lc = lane & 15;

  short8 wfrag[4][2][4];
#pragma unroll
  for (int g = 0; g < 4; ++g)
#pragma unroll
    for (int db = 0; db < 2; ++db)
#pragma unroll
      for (int kt = 0; kt < 4; ++kt) {
        const float* p =
            &W_hh[(g * 128 + wv * 32 + db * 16 + lc) * 128 + kt * 32 + lq * 8];
        f32x4 a = *(const f32x4*)p;
        f32x4 b = *(const f32x4*)(p + 4);
        short8 w;
        w[0] = f2bs(a[0]); w[1] = f2bs(a[1]); w[2] = f2bs(a[2]); w[3] = f2bs(a[3]);
        w[4] = f2bs(b[0]); w[5] = f2bs(b[1]); w[6] = f2bs(b[2]); w[7] = f2bs(b[3]);
        wfrag[g][db][kt] = w;
      }

  const int batch = blockIdx.x;
  if (tid < BATCH) {
    int gidx = batch * BATCH + tid;
    int node = 0, c = 0;
    if (gidx < NN) {
      node = order[gidx];
      c = ends[node] - starts[node]; c = c > MAXD ? MAXD : c;
    }
    nodes_s[tid] = node;
    cnts_s[tid] = c;
  }
  __syncthreads();
  for (int idx = tid; idx < BATCH * HPAD / 2; idx += 256)
    ((int*)h_s[0])[idx] = 0;
  for (int idx = tid; idx < BATCH * MAXD; idx += 256) {
    int m = idx / MAXD, p = idx - m * MAXD;
    nbr_s[m][p] = (unsigned short)nbr[nodes_s[m] * MAXD + p];
  }
  __syncthreads();
  const int T = cnts_s[0];  // descending sort -> batch max

  int cp[2];
#pragma unroll
  for (int mt = 0; mt < 2; ++mt) {
    int p = 0;
#pragma unroll
    for (int r = 0; r < 4; ++r) p |= cnts_s[mt * 16 + lq * 4 + r] << (r * 8);
    cp[mt] = p;
  }

  float c_v[2][2][4];
  s16x4 hvp[2][2];
#pragma unroll
  for (int mt = 0; mt < 2; ++mt)
#pragma unroll
    for (int db = 0; db < 2; ++db) {
#pragma unroll
      for (int r = 0; r < 4; ++r) c_v[mt][db][r] = 0.0f;
      hvp[mt][db] = (s16x4){0, 0, 0, 0};
    }

  const int pcol = (wv * 16 + lc) * 8;
  if (T > 0) {
#pragma unroll
    for (int mt = 0; mt < 2; ++mt)
#pragma unroll
      for (int r = 0; r < 4; ++r) {
        int m = mt * 16 + lq * 4 + r;
        int nb_i = (0 < ((cp[mt] >> (r * 8)) & 255)) ? (int)nbr_s[m][0] : 0;
        gl_lds16(&proj[nb_i * NG + pcol], &pbuf[wv][mt * 4 + r][0]);
      }
  }

  for (int t = 0; t < T; ++t) {
    __syncthreads();
    const short* hb = h_s[t & 1];
    short* hw = h_s[(t + 1) & 1];
    const int tn = t + 1;
    const int ts = tn < MAXD ? tn : 0;
#pragma unroll
    for (int mt = 0; mt < 2; ++mt) {
      short8 pv[4];
#pragma unroll
      for (int r = 0; r < 4; ++r)
        pv[r] = *(const short8*)&pbuf[wv][mt * 4 + r][lane * 8];
      f32x4 acc[4][2];
#pragma unroll
      for (int g = 0; g < 4; ++g)
#pragma unroll
        for (int db = 0; db < 2; ++db)
#pragma unroll
          for (int r = 0; r < 4; ++r)
            acc[g][db][r] = bs2f(pv[r][g * 2 + db]);
      __builtin_amdgcn_sched_barrier(0);
      if (tn < T) {
#pragma unroll
        for (int r = 0; r < 4; ++r) {
          int m = mt * 16 + lq * 4 + r;
          int nb_i = (tn < ((cp[mt] >> (r * 8)) & 255)) ? (int)nbr_s[m][ts] : 0;
          gl_lds16(&proj[nb_i * NG + pcol], &pbuf[wv][mt * 4 + r][0]);
        }
      }
      __builtin_amdgcn_sched_barrier(0);
      short8 afrag[4];
#pragma unroll
      for (int kt = 0; kt < 4; ++kt)
        afrag[kt] = *(const short8*)&hb[(mt * 16 + lc) * HPAD + kt * 32 + lq * 8];
#pragma unroll
      for (int g = 0; g < 4; ++g)
#pragma unroll
        for (int db = 0; db < 2; ++db)
#pragma unroll
          for (int kt = 0; kt < 4; ++kt)
            acc[g][db] = __builtin_amdgcn_mfma_f32_16x16x32_bf16(
                afrag[kt], wfrag[g][db][kt], acc[g][db], 0, 0, 0);
#pragma unroll
      for (int db = 0; db < 2; ++db)
#pragma unroll
        for (int r = 0; r < 4; ++r) {
          float iv = sigf(acc[0][db][r]);
          float fv = sigf(acc[1][db][r]);
          float gv = tanh_(acc[2][db][r]);
          float ov = sigf(acc[3][db][r]);
          float c2 = fv * c_v[mt][db][r] + iv * gv;
          float h2 = ov * tanh_(c2);
          if (t < ((cp[mt] >> (r * 8)) & 255)) {
            c_v[mt][db][r] = c2;
            hvp[mt][db][r] = f2bs(h2);
          }
        }
#pragma unroll
      for (int db = 0; db < 2; ++db)
#pragma unroll
        for (int r = 0; r < 4; ++r)
          hw[(mt * 16 + lq * 4 + r) * HPAD + wv * 32 + db * 16 + lc] =
              hvp[mt][db][r];
    }
  }
  __syncthreads();
  const short* hf = h_s[T & 1];
  for (int idx = tid; idx < BATCH * 128; idx += 256) {
    int m = idx >> 7, d = idx & 127;
    if (batch * BATCH + m < NN) agg[nodes_s[m] * 128 + d] = hf[m * HPAD + d];
  }
}

// ---- out = [x | h] @ W_out, bf16 MFMA. db-outer unroll-1: halves wf live
// set (64->32 regs) to stay under the 128-reg 2-wave cap without spill. ----
__global__ __launch_bounds__(256, 2) void k_out(
    const float* __restrict__ x, const short* __restrict__ agg,
    const float* __restrict__ Wout, float* __restrict__ out) {
  __shared__ __align__(16) short xs[64 * 272];
  const int tid = threadIdx.x;
  const int wv = tid >> 6, lane = tid & 63, lq = lane >> 4, lc = lane & 15;
  const int base = blockIdx.x * 64;

  for (int idx4 = tid; idx4 < 64 * 32; idx4 += 256) {
    int row = idx4 >> 5, k4 = (idx4 & 31) << 2;
    f32x4 v = (f32x4){0.f, 0.f, 0.f, 0.f};
    if (base + row < NN) v = *(const f32x4*)&x[(base + row) * 128 + k4];
    s16x4 p; p[0] = f2bs(v[0]); p[1] = f2bs(v[1]); p[2] = f2bs(v[2]); p[3] = f2bs(v[3]);
    *(s16x4*)&xs[row * 272 + k4] = p;
    s16x4 a = (s16x4){0, 0, 0, 0};
    if (base + row < NN) a = *(const s16x4*)&agg[(base + row) * 128 + k4];
    *(s16x4*)&xs[row * 272 + 128 + k4] = a;
  }
  __syncthreads();

#pragma unroll 1
  for (int db = 0; db < 2; ++db) {
    short8 wf[8];
#pragma unroll
    for (int kt = 0; kt < 8; ++kt) {
      short8 w;
#pragma unroll
      for (int jj = 0; jj < 8; ++jj)
        w[jj] = f2bs(Wout[(kt * 32 + lq * 8 + jj) * 128 + wv * 32 + db * 16 + lc]);
      wf[kt] = w;
    }
#pragma unroll
    for (int mt = 0; mt < 4; ++mt) {
      short8 afrag[8];
#pragma unroll
      for (int kt = 0; kt < 8; ++kt)
        afrag[kt] = *(const short8*)&xs[(mt * 16 + lc) * 272 + kt * 32 + lq * 8];
      f32x4 acc = (f32x4){0.f, 0.f, 0.f, 0.f};
#pragma unroll
      for (int kt = 0; kt < 8; ++kt)
        acc = __builtin_amdgcn_mfma_f32_16x16x32_bf16(afrag[kt], wf[kt], acc,
                                                      0, 0, 0);
#pragma unroll
      for (int r = 0; r < 4; ++r) {
        int row = base + mt * 16 + lq * 4 + r;
        if (row < NN)
          out[row * 128 + wv * 32 + db * 16 + lc] = acc[r];
      }
    }
  }
}

extern "C" void kernel_launch(void* const* d_in, const int* in_sizes, int n_in,
                              void* d_out, int out_size, void* d_ws,
                              size_t ws_size, hipStream_t stream) {
  (void)in_sizes; (void)n_in; (void)out_size; (void)ws_size;
  const float* x     = (const float*)d_in[0];
  const float* W_ih  = (const float*)d_in[1];
  const float* W_hh  = (const float*)d_in[2];
  const float* b_ih  = (const float*)d_in[3];
  const float* b_hh  = (const float*)d_in[4];
  const float* W_out = (const float*)d_in[5];
  const int*   esrc  = (const int*)d_in[6];
  const int*   etrg  = (const int*)d_in[7];
  float* out = (float*)d_out;
  char* ws = (char*)d_ws;

  int*   starts = (int*)(ws + 0);          // 120000 B
  int*   ends   = (int*)(ws + 120064);     // 120000 B
  int*   offs   = (int*)(ws + 240128);     // 196 B
  int*   order  = (int*)(ws + 240384);     // 120000 B
  int*   nbr    = (int*)(ws + 360448);     // 5,760,000 B
  short* proj   = (short*)(ws + 6382848);  // 30,720,000 B (bf16, permuted cols)
  short* agg    = (short*)(ws + 37102848); // 7,680,000 B (bf16)

  (void)hipMemsetAsync(d_ws, 0, 240128, stream);  // starts + ends

  k_edges  <<<1875, 256, 0, stream>>>(esrc, starts, ends);
  k_hs     <<<1, 1024, 0, stream>>>(starts, ends, offs);
  k_scatter<<<118, 256, 0, stream>>>(starts, ends, offs, order);
  k_nbr    <<<1875, 256, 0, stream>>>(esrc, etrg, starts, nbr);
  k_proj   <<<NGB, 256, 0, stream>>>(x, W_ih, b_ih, b_hh, proj);
  k_lstm   <<<NB, 256, 0, stream>>>(W_hh, proj, order, starts, ends, nbr, agg);
  k_out    <<<NGB, 256, 0, stream>>>(x, agg, W_out, out);
}